// Round 1
// baseline (388.460 us; speedup 1.0000x reference)
//
#include <hip/hip_runtime.h>
#include <hip/hip_bf16.h>

#define BB 4
#define NN 1024
#define FF 256
#define NBLK 1024
#define NTHR 256

typedef __hip_bfloat16 bf16;
typedef unsigned long long u64;
typedef unsigned int u32;
typedef unsigned short u16;
typedef unsigned char u8;

__device__ __forceinline__ bf16 f2b(float v) { return __float2bfloat16(v); }
__device__ __forceinline__ u16 f2bbits(float v) {
    bf16 h = __float2bfloat16(v);
    u16 s; __builtin_memcpy(&s, &h, 2);
    return s;
}
template <typename OT> __device__ __forceinline__ OT fromf(float v);
template <> __device__ __forceinline__ float fromf<float>(float v) { return v; }
template <> __device__ __forceinline__ bf16 fromf<bf16>(float v) { return __float2bfloat16(v); }

// ---------------------------------------------------------------------------
// Grid barrier: monotonic arrival counter in workspace (zeroed per launch by
// hipMemsetAsync). Agent-scope release on arrival (L2 writeback) + one
// agent-scope acquire after the spin (L2/L1 invalidate) give cross-XCD
// visibility that kernel boundaries used to provide. Residency is guaranteed
// by arithmetic: 1024 blocks x 4 waves, launch_bounds(256,4) caps VGPR<=128
// -> 16 waves/CU, LDS 8.2KB -> 4 blocks/CU exactly covers the grid.
// Bailout (wrong answer, visible failure) instead of a hang if that breaks.
// ---------------------------------------------------------------------------
__device__ __forceinline__ void grid_sync(int* bar, int target) {
    __syncthreads();
    if (threadIdx.x == 0) {
        __hip_atomic_fetch_add(bar, 1, __ATOMIC_RELEASE, __HIP_MEMORY_SCOPE_AGENT);
        int spins = 0;
        while (__hip_atomic_load(bar, __ATOMIC_RELAXED, __HIP_MEMORY_SCOPE_AGENT) < target) {
            __builtin_amdgcn_s_sleep(8);
            if (++spins > (1 << 22)) break;
        }
        (void)__hip_atomic_load(bar, __ATOMIC_ACQUIRE, __HIP_MEMORY_SCOPE_AGENT);
    }
    __syncthreads();
}

// ---------------------------------------------------------------------------
// Single persistent kernel, 4 phases separated by grid barriers:
//  A: bit-pack adj rows (4 rows/block) + rank-sort (blocks 0-7, 2 per batch)
//  B: inc bits + packed select rows (4 rows/block, s2nT hoisted per block)
//  C: blocks 0-3 greedy K-MIS (L2-warm + serial);  blocks 4+ zero d_out
//  D: outputs for k < K only (k >= K regions already zeroed in phase C)
// ---------------------------------------------------------------------------
template <typename OT>
__global__ __launch_bounds__(NTHR, 4) void mega_kernel(
        const float* __restrict__ x, const float* __restrict__ adj,
        const float* __restrict__ pos, const float* __restrict__ order,
        u64* __restrict__ bitsA, u32* __restrict__ packed,
        int* __restrict__ sp2node, int* __restrict__ node2sp,
        int* __restrict__ perm, int* __restrict__ kcnt,
        int* __restrict__ sink, int* __restrict__ bar,
        OT* __restrict__ out, size_t out_elems)
{
    const int B = blockIdx.x, t = threadIdx.x;
    __shared__ union ShU {
        u64 keys[NN];                                   // phase A sort: 8192B
        struct {                                        // phase B: ~6.9KB
            u64 myrow[16], incw[16], part[256];
            int s2nT[16 * 65];
            unsigned short nbr[192];
            int cnt;
        } pb;
        struct { u8 selS[NN]; } pc;                     // phase C: 1KB
        struct {                                        // phase D: ~7.2KB
            int p[NN];
            u64 myrow[16];
            unsigned short nbr[192];
            u16 stx[FF], sta[NN];
            int cnt;
        } pd;
    } sh;

    // ---------------- Phase A: pack bits + rank sort ----------------
    for (int i = 0; i < 4; i++) {
        const int id = B * 4 + i;                       // 0..4095
        const int b = id >> 10, r = id & (NN - 1);
        const size_t base = (size_t)b * NN * NN + (size_t)r * NN;
        for (int q = 0; q < 4; q++) {
            int j = q * 256 + t;
            u64 bal = __ballot(adj[base + j] != 0.0f);
            if ((t & 63) == 0) bitsA[((size_t)b * NN + r) * 16 + (j >> 6)] = bal;
        }
    }
    if (B < 8) {                                        // 2 sort blocks per batch
        const int b = B >> 1, half = B & 1;
        for (int i = t; i < NN; i += NTHR) {
            float v = order[(size_t)b * NN + i];
            u32 ub = __float_as_uint(v);
            u32 sk = (ub & 0x80000000u) ? ~ub : (ub | 0x80000000u);
            sh.keys[i] = ((u64)sk << 32) | (u32)i;      // strict total order
        }
        __syncthreads();
        u64 mk0 = sh.keys[half * 512 + t], mk1 = sh.keys[half * 512 + 256 + t];
        int r0 = 0, r1 = 0;
        for (int m = 0; m < NN; m++) {                  // LDS broadcast reads
            u64 v = sh.keys[m];
            r0 += (v < mk0);
            r1 += (v < mk1);
        }
        int n0 = (int)(mk0 & 0xFFFFFFFFu), n1 = (int)(mk1 & 0xFFFFFFFFu);
        sp2node[b * NN + r0] = n0; node2sp[b * NN + n0] = r0;
        sp2node[b * NN + r1] = n1; node2sp[b * NN + n1] = r1;
    }
    grid_sync(bar, NBLK);

    // ---------------- Phase B: inc bits + packed rows ----------------
    {
        const int b = B >> 8, rbase = (B & 255) * 4;    // 4 rows, same batch
        for (int q = 0; q < 4; q++) {                   // s2nT once per block
            int j = q * 256 + t;
            sh.pb.s2nT[(j & 15) * 65 + (j >> 4)] = sp2node[b * NN + j];
        }
        for (int rr = 0; rr < 4; rr++) {
            const int r = rbase + rr;
            if (t == 0) sh.pb.cnt = 0;
            if (t < 16) sh.pb.myrow[t] = bitsA[((size_t)b * NN + r) * 16 + t];
            __syncthreads();
            for (int q = 0; q < 4; q++) {
                int j = q * 256 + t;
                if ((sh.pb.myrow[j >> 6] >> (j & 63)) & 1) {
                    int p = atomicAdd(&sh.pb.cnt, 1);
                    if (p < 192) sh.pb.nbr[p] = (unsigned short)j;
                }
            }
            __syncthreads();
            const int c = min(sh.pb.cnt, 192);
            {   // parallel OR of neighbor rows: t = g*16 + w
                const int w = t & 15, g = t >> 4;
                u64 v = 0;
                for (int n = g; n < c; n += 16)
                    v |= bitsA[((size_t)b * NN + sh.pb.nbr[n]) * 16 + w];
                sh.pb.part[t] = v;
            }
            __syncthreads();
            if (t < 16) {
                u64 acc = sh.pb.myrow[t];
                for (int g = 0; g < 16; g++) acc |= sh.pb.part[g * 16 + t];
                sh.pb.incw[t] = acc;
            }
            __syncthreads();
            if (t < 64) {
                const int s = node2sp[b * NN + r];
                u32 e16 = 0, i16 = 0;
                for (int q = 0; q < 16; q++) {
                    int jn = sh.pb.s2nT[q * 65 + t];
                    u32 eb = (u32)((sh.pb.myrow[jn >> 6] >> (jn & 63)) & 1) | (u32)(jn == r);
                    u32 ib = (u32)((sh.pb.incw[jn >> 6] >> (jn & 63)) & 1);
                    e16 |= eb << q;
                    i16 |= ib << q;
                }
                packed[((size_t)b * NN + s) * 64 + t] = e16 | (i16 << 16);
            }
            __syncthreads();                            // protect reuse
        }
    }
    grid_sync(bar, 2 * NBLK);

    // ---------------- Phase C: select (blocks 0-3) || zero outputs ----------------
    if (B < 4) {
        const int b = B;
        const uint4* pp = (const uint4*)(packed + (size_t)b * NN * 64);
        u32 acc = 0;                                    // warm local-XCD L2
        for (int i = t; i < NN * 16; i += NTHR) {
            uint4 v = pp[i];
            acc ^= v.x ^ v.y ^ v.z ^ v.w;
        }
        if (acc == 0xDEADBEEFu) atomicAdd(sink, 1);     // keep loads live
        __syncthreads();

        if (t < 64) {
            const int l = t;
            u32 avail = 0xFFFFu, front = (l == 0) ? 1u : 0u, sel = 0u;
            int cur = 0;                                // sorted pos 0 = argmin(order)
            for (int iter = 0; iter < 2 * NN + 8; ++iter) {
                if ((cur >> 4) == l) sel |= 1u << (cur & 15);
                u32 p = packed[((size_t)b * NN + cur) * 64 + l];
                avail &= ~(p & 0xFFFFu);                // exc (incl. diag)
                front = (front | (p >> 16)) & avail;
                u64 fb = __ballot(front != 0u);
                if (!fb) {                              // fused restart
                    front = avail;
                    fb = __ballot(front != 0u);
                    if (!fb) break;
                }
                int lf = __ffsll(fb) - 1;
                u32 f = __shfl(front, lf);
                cur = lf * 16 + (__ffs(f) - 1);
            }
            for (int q = 0; q < 16; q++) sh.pc.selS[l * 16 + q] = (sel >> q) & 1u;
        }
        __syncthreads();
        if (t < 64) {
            const int l = t;
            u32 nodesel = 0;
            const int* n2s = node2sp + b * NN;
            for (int q = 0; q < 16; q++)
                nodesel |= ((u32)sh.pc.selS[n2s[l * 16 + q]]) << q;
            int cnt_sel = __popc(nodesel);
            int ps = cnt_sel;
            for (int off = 1; off < 64; off <<= 1) {
                int v = __shfl_up(ps, off);
                if (l >= off) ps += v;
            }
            const int K = __shfl(ps, 63);
            int pos_ = ps - cnt_sel;
            u32 m = nodesel;
            while (m) { int i = __ffs(m) - 1; perm[b * NN + pos_++] = l * 16 + i; m &= m - 1; }
            int posu = K + l * 16 - (ps - cnt_sel);
            m = (~nodesel) & 0xFFFFu;
            while (m) { int i = __ffs(m) - 1; perm[b * NN + posu++] = l * 16 + i; m &= m - 1; }
            if (l == 0) kcnt[b] = K;
        }
    } else {
        // zero entire d_out (covers k>=K rows, padding, mask) during select
        const size_t nu4 = (out_elems * sizeof(OT)) >> 4;
        uint4 z = make_uint4(0, 0, 0, 0);
        uint4* o4 = (uint4*)out;
        for (size_t i = (size_t)(B - 4) * NTHR + t; i < nu4; i += (size_t)(NBLK - 4) * NTHR)
            o4[i] = z;
    }
    grid_sync(bar, 3 * NBLK);

    // ---------------- Phase D: outputs for k < K only ----------------
    OT* out_x = out;
    OT* out_pos = out_x + (size_t)BB * NN * FF;
    OT* out_a = out_pos + (size_t)BB * NN * 3;
    OT* out_mask = out_a + (size_t)BB * NN * NN;

    for (int task = B; task < BB * NN; task += NBLK) {
        const int b = task >> 10, k = task & (NN - 1);
        const int K = kcnt[b];
        if (k >= K) continue;                           // block-uniform
        const int r = perm[b * NN + k];
        OT* ox = out_x + ((size_t)b * NN + k) * FF;
        OT* op = out_pos + ((size_t)b * NN + k) * 3;
        OT* oa = out_a + ((size_t)b * NN + k) * NN;
        if (t == 0) {
            out_mask[(size_t)b * NN + k] = fromf<OT>(1.0f);
            sh.pd.cnt = 0;
        }
        if (t < 16) sh.pd.myrow[t] = bitsA[((size_t)b * NN + r) * 16 + t];
        for (int q = 0; q < 4; q++) { int j = t + q * 256; sh.pd.p[j] = perm[b * NN + j]; }
        __syncthreads();
        for (int i = 0; i < 4; i++) {
            int j = i * 256 + t;
            if ((sh.pd.myrow[j >> 6] >> (j & 63)) & 1) {
                int pp = atomicAdd(&sh.pd.cnt, 1);
                if (pp < 192) sh.pd.nbr[pp] = (unsigned short)j;
            }
        }
        __syncthreads();
        const int c = min(sh.pd.cnt, 192);

        // pool: x_p[k] = x[r] + sum_n x[nbr]; pos_p = (...)/(c+1)
        const size_t xb = (size_t)b * NN * FF;
        float acc = x[xb + (size_t)r * FF + t];
        for (int n = 0; n < c; n++) acc += x[xb + (size_t)sh.pd.nbr[n] * FF + t];
        if (t < 3) {
            const size_t pb_ = (size_t)b * NN * 3;
            float pa = pos[pb_ + r * 3 + t];
            for (int n = 0; n < c; n++) pa += pos[pb_ + sh.pd.nbr[n] * 3 + t];
            op[t] = fromf<OT>(pa / (float)(c + 1));
        }

        if constexpr (sizeof(OT) == 2) {
            sh.pd.stx[t] = f2bbits(acc);
            for (int q = 0; q < 4; q++) {
                int jj = t + q * 256;
                float v = 0.0f;
                if (jj < K) {
                    const int pj = sh.pd.p[jj];
                    const u64* rj = bitsA + ((size_t)b * NN + pj) * 16;
                    int a2 = (int)((sh.pd.myrow[pj >> 6] >> (pj & 63)) & 1);
#pragma unroll
                    for (int w = 0; w < 16; w++)
                        a2 += __popcll(sh.pd.myrow[w] & rj[w]);
                    v = (float)a2;
                }
                sh.pd.sta[jj] = f2bbits(v);
            }
            __syncthreads();
            const int nu = (K + 7) >> 3;                // only real columns; rest pre-zeroed
            if (t < nu) ((uint4*)oa)[t] = ((const uint4*)sh.pd.sta)[t];
            if (t < 32) ((uint4*)ox)[t] = ((const uint4*)sh.pd.stx)[t];
            __syncthreads();
        } else {
            ox[t] = acc;
            for (int q = 0; q < 4; q++) {
                int jj = t + q * 256;
                if (jj < K) {
                    const int pj = sh.pd.p[jj];
                    const u64* rj = bitsA + ((size_t)b * NN + pj) * 16;
                    int a2 = (int)((sh.pd.myrow[pj >> 6] >> (pj & 63)) & 1);
#pragma unroll
                    for (int w = 0; w < 16; w++)
                        a2 += __popcll(sh.pd.myrow[w] & rj[w]);
                    oa[jj] = (float)a2;
                }
            }
            __syncthreads();
        }
    }
}

extern "C" void kernel_launch(void* const* d_in, const int* in_sizes, int n_in,
                              void* d_out, int out_size, void* d_ws, size_t ws_size,
                              hipStream_t stream) {
    const float* x     = (const float*)d_in[0];  // [B,N,F]
    const float* adj   = (const float*)d_in[1];  // [B,N,N]
    const float* pos   = (const float*)d_in[2];  // [B,N,3]
    const float* order = (const float*)d_in[3];  // [B,N]
    // d_in[4] = node_mask: all-true; ignored.

    char* ws = (char*)d_ws;
    size_t off = 0;
    u64* bitsA   = (u64*)(ws + off); off += (size_t)BB * NN * 16 * 8;   // 512 KiB
    u32* packed  = (u32*)(ws + off); off += (size_t)BB * NN * 64 * 4;   // 1 MiB
    int* sp2node = (int*)(ws + off); off += (size_t)BB * NN * 4;
    int* node2sp = (int*)(ws + off); off += (size_t)BB * NN * 4;
    int* perm    = (int*)(ws + off); off += (size_t)BB * NN * 4;
    int* kcnt    = (int*)(ws + off); off += 64;
    int* sink    = (int*)(ws + off); off += 64;   // DCE-defeat target, never read
    int* bar     = (int*)(ws + off); off += 64;   // grid-barrier arrival counter

    hipMemsetAsync(bar, 0, 64, stream);           // ws is poisoned; barrier needs 0

    bool outf32 = false;
    size_t osz = 0;
    if (hipMemPtrGetInfo(d_out, &osz) == hipSuccess)
        outf32 = (osz >= 4ull * (size_t)out_size);

    if (outf32)
        mega_kernel<float><<<NBLK, NTHR, 0, stream>>>(x, adj, pos, order, bitsA, packed,
            sp2node, node2sp, perm, kcnt, sink, bar, (float*)d_out, (size_t)out_size);
    else
        mega_kernel<bf16><<<NBLK, NTHR, 0, stream>>>(x, adj, pos, order, bitsA, packed,
            sp2node, node2sp, perm, kcnt, sink, bar, (bf16*)d_out, (size_t)out_size);
}

// Round 2
// 255.858 us; speedup vs baseline: 1.5183x; 1.5183x over previous
//
#include <hip/hip_runtime.h>
#include <hip/hip_bf16.h>

#define BB 4
#define NN 1024
#define FF 256
#define NBLK 1024
#define NTHR 256

typedef __hip_bfloat16 bf16;
typedef unsigned long long u64;
typedef unsigned int u32;
typedef unsigned short u16;
typedef unsigned char u8;

__device__ __forceinline__ bf16 f2b(float v) { return __float2bfloat16(v); }
__device__ __forceinline__ u16 f2bbits(float v) {
    bf16 h = __float2bfloat16(v);
    u16 s; __builtin_memcpy(&s, &h, 2);
    return s;
}
template <typename OT> __device__ __forceinline__ OT fromf(float v);
template <> __device__ __forceinline__ float fromf<float>(float v) { return v; }
template <> __device__ __forceinline__ bf16 fromf<bf16>(float v) { return __float2bfloat16(v); }

// ---------------------------------------------------------------------------
// Grid barrier v2 — tree arrival + broadcast flag.
// Round-1 version put 1024 same-line RMWs AND all spin polls on ONE line at
// the cross-XCD coherence point (~90us/barrier measured). Now:
//   - 64 group counters, 128B apart: 16 RMWs each, parallel across lines.
//   - group leaders (arrival == phase*16-1) RMW a root line (64 RMWs).
//   - last leader release-stores flag = phase on its OWN line.
//   - everyone polls the read-only flag with SYSTEM-scope relaxed loads
//     (policy bits force bypass of the non-coherent local L2 -> always fresh,
//     and NO invalidate side effects that would nuke select's warm L2),
//     s_sleep(32) backoff.
// Counters are monotonic across the 3 barriers (no reset race).
// Layout (ints): [0]=root, [32]=flag, [64+32*g]=group g.  9216 B, memset 0.
// ---------------------------------------------------------------------------
__device__ __forceinline__ void grid_sync(int* bars, int phase) {
    __syncthreads();
    if (threadIdx.x == 0) {
        int* root = bars;
        int* flag = bars + 32;
        int* gc   = bars + 64 + ((blockIdx.x >> 4) << 5);
        int v = __hip_atomic_fetch_add(gc, 1, __ATOMIC_ACQ_REL, __HIP_MEMORY_SCOPE_AGENT);
        if (v == phase * 16 - 1) {                       // last of my 16-block group
            int r = __hip_atomic_fetch_add(root, 1, __ATOMIC_ACQ_REL, __HIP_MEMORY_SCOPE_AGENT);
            if (r == phase * 64 - 1)                     // last group
                __hip_atomic_store(flag, phase, __ATOMIC_RELEASE, __HIP_MEMORY_SCOPE_AGENT);
        }
        int spins = 0;
        while (__hip_atomic_load(flag, __ATOMIC_RELAXED, __HIP_MEMORY_SCOPE_SYSTEM) < phase) {
            __builtin_amdgcn_s_sleep(32);
            if (++spins > (1 << 18)) break;              // bailout: visible failure, not hang
        }
        (void)__hip_atomic_load(flag, __ATOMIC_ACQUIRE, __HIP_MEMORY_SCOPE_AGENT);
    }
    __syncthreads();
}

// ---------------------------------------------------------------------------
// Single persistent kernel, 4 phases separated by grid barriers:
//  A: bit-pack adj rows (4 rows/block) + rank-sort (blocks 0-7, 2 per batch)
//  B: inc bits + packed select rows (4 rows/block, s2nT hoisted per block)
//  C: blocks 0-3 greedy K-MIS (L2-warm + serial);  blocks 4+ zero d_out
//  D: outputs for k < K only (k >= K regions already zeroed in phase C)
// ---------------------------------------------------------------------------
template <typename OT>
__global__ __launch_bounds__(NTHR, 4) void mega_kernel(
        const float* __restrict__ x, const float* __restrict__ adj,
        const float* __restrict__ pos, const float* __restrict__ order,
        u64* __restrict__ bitsA, u32* __restrict__ packed,
        int* __restrict__ sp2node, int* __restrict__ node2sp,
        int* __restrict__ perm, int* __restrict__ kcnt,
        int* __restrict__ sink, int* __restrict__ bar,
        OT* __restrict__ out, size_t out_elems)
{
    const int B = blockIdx.x, t = threadIdx.x;
    __shared__ union ShU {
        u64 keys[NN];                                   // phase A sort: 8192B
        struct {                                        // phase B: ~6.9KB
            u64 myrow[16], incw[16], part[256];
            int s2nT[16 * 65];
            unsigned short nbr[192];
            int cnt;
        } pb;
        struct { u8 selS[NN]; } pc;                     // phase C: 1KB
        struct {                                        // phase D: ~7.2KB
            int p[NN];
            u64 myrow[16];
            unsigned short nbr[192];
            u16 stx[FF], sta[NN];
            int cnt;
        } pd;
    } sh;

    // ---------------- Phase A: pack bits + rank sort ----------------
    for (int i = 0; i < 4; i++) {
        const int id = B * 4 + i;                       // 0..4095
        const int b = id >> 10, r = id & (NN - 1);
        const size_t base = (size_t)b * NN * NN + (size_t)r * NN;
        for (int q = 0; q < 4; q++) {
            int j = q * 256 + t;
            u64 bal = __ballot(adj[base + j] != 0.0f);
            if ((t & 63) == 0) bitsA[((size_t)b * NN + r) * 16 + (j >> 6)] = bal;
        }
    }
    if (B < 8) {                                        // 2 sort blocks per batch
        const int b = B >> 1, half = B & 1;
        for (int i = t; i < NN; i += NTHR) {
            float v = order[(size_t)b * NN + i];
            u32 ub = __float_as_uint(v);
            u32 sk = (ub & 0x80000000u) ? ~ub : (ub | 0x80000000u);
            sh.keys[i] = ((u64)sk << 32) | (u32)i;      // strict total order
        }
        __syncthreads();
        u64 mk0 = sh.keys[half * 512 + t], mk1 = sh.keys[half * 512 + 256 + t];
        int r0 = 0, r1 = 0;
        for (int m = 0; m < NN; m++) {                  // LDS broadcast reads
            u64 v = sh.keys[m];
            r0 += (v < mk0);
            r1 += (v < mk1);
        }
        int n0 = (int)(mk0 & 0xFFFFFFFFu), n1 = (int)(mk1 & 0xFFFFFFFFu);
        sp2node[b * NN + r0] = n0; node2sp[b * NN + n0] = r0;
        sp2node[b * NN + r1] = n1; node2sp[b * NN + n1] = r1;
    }
    grid_sync(bar, 1);

    // ---------------- Phase B: inc bits + packed rows ----------------
    {
        const int b = B >> 8, rbase = (B & 255) * 4;    // 4 rows, same batch
        for (int q = 0; q < 4; q++) {                   // s2nT once per block
            int j = q * 256 + t;
            sh.pb.s2nT[(j & 15) * 65 + (j >> 4)] = sp2node[b * NN + j];
        }
        for (int rr = 0; rr < 4; rr++) {
            const int r = rbase + rr;
            if (t == 0) sh.pb.cnt = 0;
            if (t < 16) sh.pb.myrow[t] = bitsA[((size_t)b * NN + r) * 16 + t];
            __syncthreads();
            for (int q = 0; q < 4; q++) {
                int j = q * 256 + t;
                if ((sh.pb.myrow[j >> 6] >> (j & 63)) & 1) {
                    int p = atomicAdd(&sh.pb.cnt, 1);
                    if (p < 192) sh.pb.nbr[p] = (unsigned short)j;
                }
            }
            __syncthreads();
            const int c = min(sh.pb.cnt, 192);
            {   // parallel OR of neighbor rows: t = g*16 + w
                const int w = t & 15, g = t >> 4;
                u64 v = 0;
                for (int n = g; n < c; n += 16)
                    v |= bitsA[((size_t)b * NN + sh.pb.nbr[n]) * 16 + w];
                sh.pb.part[t] = v;
            }
            __syncthreads();
            if (t < 16) {
                u64 acc = sh.pb.myrow[t];
                for (int g = 0; g < 16; g++) acc |= sh.pb.part[g * 16 + t];
                sh.pb.incw[t] = acc;
            }
            __syncthreads();
            if (t < 64) {
                const int s = node2sp[b * NN + r];
                u32 e16 = 0, i16 = 0;
                for (int q = 0; q < 16; q++) {
                    int jn = sh.pb.s2nT[q * 65 + t];
                    u32 eb = (u32)((sh.pb.myrow[jn >> 6] >> (jn & 63)) & 1) | (u32)(jn == r);
                    u32 ib = (u32)((sh.pb.incw[jn >> 6] >> (jn & 63)) & 1);
                    e16 |= eb << q;
                    i16 |= ib << q;
                }
                packed[((size_t)b * NN + s) * 64 + t] = e16 | (i16 << 16);
            }
            __syncthreads();                            // protect reuse
        }
    }
    grid_sync(bar, 2);

    // ---------------- Phase C: select (blocks 0-3) || zero outputs ----------------
    if (B < 4) {
        const int b = B;
        const uint4* pp = (const uint4*)(packed + (size_t)b * NN * 64);
        u32 acc = 0;                                    // warm local-XCD L2
        for (int i = t; i < NN * 16; i += NTHR) {
            uint4 v = pp[i];
            acc ^= v.x ^ v.y ^ v.z ^ v.w;
        }
        if (acc == 0xDEADBEEFu) atomicAdd(sink, 1);     // keep loads live
        __syncthreads();

        if (t < 64) {
            const int l = t;
            u32 avail = 0xFFFFu, front = (l == 0) ? 1u : 0u, sel = 0u;
            int cur = 0;                                // sorted pos 0 = argmin(order)
            for (int iter = 0; iter < 2 * NN + 8; ++iter) {
                if ((cur >> 4) == l) sel |= 1u << (cur & 15);
                u32 p = packed[((size_t)b * NN + cur) * 64 + l];
                avail &= ~(p & 0xFFFFu);                // exc (incl. diag)
                front = (front | (p >> 16)) & avail;
                u64 fb = __ballot(front != 0u);
                if (!fb) {                              // fused restart
                    front = avail;
                    fb = __ballot(front != 0u);
                    if (!fb) break;
                }
                int lf = __ffsll(fb) - 1;
                u32 f = __shfl(front, lf);
                cur = lf * 16 + (__ffs(f) - 1);
            }
            for (int q = 0; q < 16; q++) sh.pc.selS[l * 16 + q] = (sel >> q) & 1u;
        }
        __syncthreads();
        if (t < 64) {
            const int l = t;
            u32 nodesel = 0;
            const int* n2s = node2sp + b * NN;
            for (int q = 0; q < 16; q++)
                nodesel |= ((u32)sh.pc.selS[n2s[l * 16 + q]]) << q;
            int cnt_sel = __popc(nodesel);
            int ps = cnt_sel;
            for (int off = 1; off < 64; off <<= 1) {
                int v = __shfl_up(ps, off);
                if (l >= off) ps += v;
            }
            const int K = __shfl(ps, 63);
            int pos_ = ps - cnt_sel;
            u32 m = nodesel;
            while (m) { int i = __ffs(m) - 1; perm[b * NN + pos_++] = l * 16 + i; m &= m - 1; }
            int posu = K + l * 16 - (ps - cnt_sel);
            m = (~nodesel) & 0xFFFFu;
            while (m) { int i = __ffs(m) - 1; perm[b * NN + posu++] = l * 16 + i; m &= m - 1; }
            if (l == 0) kcnt[b] = K;
        }
    } else {
        // zero entire d_out (covers k>=K rows, padding, mask) during select
        const size_t nu4 = (out_elems * sizeof(OT)) >> 4;
        uint4 z = make_uint4(0, 0, 0, 0);
        uint4* o4 = (uint4*)out;
        for (size_t i = (size_t)(B - 4) * NTHR + t; i < nu4; i += (size_t)(NBLK - 4) * NTHR)
            o4[i] = z;
    }
    grid_sync(bar, 3);

    // ---------------- Phase D: outputs for k < K only ----------------
    OT* out_x = out;
    OT* out_pos = out_x + (size_t)BB * NN * FF;
    OT* out_a = out_pos + (size_t)BB * NN * 3;
    OT* out_mask = out_a + (size_t)BB * NN * NN;

    for (int task = B; task < BB * NN; task += NBLK) {
        const int b = task >> 10, k = task & (NN - 1);
        const int K = kcnt[b];
        if (k >= K) continue;                           // block-uniform
        const int r = perm[b * NN + k];
        OT* ox = out_x + ((size_t)b * NN + k) * FF;
        OT* op = out_pos + ((size_t)b * NN + k) * 3;
        OT* oa = out_a + ((size_t)b * NN + k) * NN;
        if (t == 0) {
            out_mask[(size_t)b * NN + k] = fromf<OT>(1.0f);
            sh.pd.cnt = 0;
        }
        if (t < 16) sh.pd.myrow[t] = bitsA[((size_t)b * NN + r) * 16 + t];
        for (int q = 0; q < 4; q++) { int j = t + q * 256; sh.pd.p[j] = perm[b * NN + j]; }
        __syncthreads();
        for (int i = 0; i < 4; i++) {
            int j = i * 256 + t;
            if ((sh.pd.myrow[j >> 6] >> (j & 63)) & 1) {
                int pp = atomicAdd(&sh.pd.cnt, 1);
                if (pp < 192) sh.pd.nbr[pp] = (unsigned short)j;
            }
        }
        __syncthreads();
        const int c = min(sh.pd.cnt, 192);

        // pool: x_p[k] = x[r] + sum_n x[nbr]; pos_p = (...)/(c+1)
        const size_t xb = (size_t)b * NN * FF;
        float acc = x[xb + (size_t)r * FF + t];
        for (int n = 0; n < c; n++) acc += x[xb + (size_t)sh.pd.nbr[n] * FF + t];
        if (t < 3) {
            const size_t pb_ = (size_t)b * NN * 3;
            float pa = pos[pb_ + r * 3 + t];
            for (int n = 0; n < c; n++) pa += pos[pb_ + sh.pd.nbr[n] * 3 + t];
            op[t] = fromf<OT>(pa / (float)(c + 1));
        }

        if constexpr (sizeof(OT) == 2) {
            sh.pd.stx[t] = f2bbits(acc);
            for (int q = 0; q < 4; q++) {
                int jj = t + q * 256;
                float v = 0.0f;
                if (jj < K) {
                    const int pj = sh.pd.p[jj];
                    const u64* rj = bitsA + ((size_t)b * NN + pj) * 16;
                    int a2 = (int)((sh.pd.myrow[pj >> 6] >> (pj & 63)) & 1);
#pragma unroll
                    for (int w = 0; w < 16; w++)
                        a2 += __popcll(sh.pd.myrow[w] & rj[w]);
                    v = (float)a2;
                }
                sh.pd.sta[jj] = f2bbits(v);
            }
            __syncthreads();
            const int nu = (K + 7) >> 3;                // only real columns; rest pre-zeroed
            if (t < nu) ((uint4*)oa)[t] = ((const uint4*)sh.pd.sta)[t];
            if (t < 32) ((uint4*)ox)[t] = ((const uint4*)sh.pd.stx)[t];
            __syncthreads();
        } else {
            ox[t] = acc;
            for (int q = 0; q < 4; q++) {
                int jj = t + q * 256;
                if (jj < K) {
                    const int pj = sh.pd.p[jj];
                    const u64* rj = bitsA + ((size_t)b * NN + pj) * 16;
                    int a2 = (int)((sh.pd.myrow[pj >> 6] >> (pj & 63)) & 1);
#pragma unroll
                    for (int w = 0; w < 16; w++)
                        a2 += __popcll(sh.pd.myrow[w] & rj[w]);
                    oa[jj] = (float)a2;
                }
            }
            __syncthreads();
        }
    }
}

extern "C" void kernel_launch(void* const* d_in, const int* in_sizes, int n_in,
                              void* d_out, int out_size, void* d_ws, size_t ws_size,
                              hipStream_t stream) {
    const float* x     = (const float*)d_in[0];  // [B,N,F]
    const float* adj   = (const float*)d_in[1];  // [B,N,N]
    const float* pos   = (const float*)d_in[2];  // [B,N,3]
    const float* order = (const float*)d_in[3];  // [B,N]
    // d_in[4] = node_mask: all-true; ignored.

    char* ws = (char*)d_ws;
    size_t off = 0;
    u64* bitsA   = (u64*)(ws + off); off += (size_t)BB * NN * 16 * 8;   // 512 KiB
    u32* packed  = (u32*)(ws + off); off += (size_t)BB * NN * 64 * 4;   // 1 MiB
    int* sp2node = (int*)(ws + off); off += (size_t)BB * NN * 4;
    int* node2sp = (int*)(ws + off); off += (size_t)BB * NN * 4;
    int* perm    = (int*)(ws + off); off += (size_t)BB * NN * 4;
    int* kcnt    = (int*)(ws + off); off += 64;
    int* sink    = (int*)(ws + off); off += 64;   // DCE-defeat target, never read
    int* bar     = (int*)(ws + off); off += 9216; // barrier tree: root/flag/64 groups

    hipMemsetAsync(bar, 0, 9216, stream);         // ws is poisoned; barrier needs 0

    bool outf32 = false;
    size_t osz = 0;
    if (hipMemPtrGetInfo(d_out, &osz) == hipSuccess)
        outf32 = (osz >= 4ull * (size_t)out_size);

    if (outf32)
        mega_kernel<float><<<NBLK, NTHR, 0, stream>>>(x, adj, pos, order, bitsA, packed,
            sp2node, node2sp, perm, kcnt, sink, bar, (float*)d_out, (size_t)out_size);
    else
        mega_kernel<bf16><<<NBLK, NTHR, 0, stream>>>(x, adj, pos, order, bitsA, packed,
            sp2node, node2sp, perm, kcnt, sink, bar, (bf16*)d_out, (size_t)out_size);
}

// Round 3
// 154.505 us; speedup vs baseline: 2.5142x; 1.6560x over previous
//
#include <hip/hip_runtime.h>
#include <hip/hip_bf16.h>

#define BB 4
#define NN 1024
#define FF 256
#define NBLK 1024
#define NTHR 256

typedef __hip_bfloat16 bf16;
typedef unsigned long long u64;
typedef unsigned int u32;
typedef unsigned short u16;
typedef unsigned char u8;

__device__ __forceinline__ bf16 f2b(float v) { return __float2bfloat16(v); }
__device__ __forceinline__ u16 f2bbits(float v) {
    bf16 h = __float2bfloat16(v);
    u16 s; __builtin_memcpy(&s, &h, 2);
    return s;
}
template <typename OT> __device__ __forceinline__ OT fromf(float v);
template <> __device__ __forceinline__ float fromf<float>(float v) { return v; }
template <> __device__ __forceinline__ bf16 fromf<bf16>(float v) { return __float2bfloat16(v); }

// Write-through stores: relaxed SYSTEM scope -> sc0|sc1, lands at the
// coherence point, never dirty in any L2. This is what makes the barrier
// fence-free (no buffer_wbl2 / buffer_inv anywhere in the kernel).
__device__ __forceinline__ void st_wt(u32* p, u32 v)   { __hip_atomic_store(p, v, __ATOMIC_RELAXED, __HIP_MEMORY_SCOPE_SYSTEM); }
__device__ __forceinline__ void st_wt(u64* p, u64 v)   { __hip_atomic_store(p, v, __ATOMIC_RELAXED, __HIP_MEMORY_SCOPE_SYSTEM); }
__device__ __forceinline__ void st_wt(int* p, int v)   { __hip_atomic_store(p, v, __ATOMIC_RELAXED, __HIP_MEMORY_SCOPE_SYSTEM); }
__device__ __forceinline__ void st_wt(float* p, float v){ __hip_atomic_store(p, v, __ATOMIC_RELAXED, __HIP_MEMORY_SCOPE_SYSTEM); }

// ---------------------------------------------------------------------------
// Grid barrier v3 — fence-free.
//  * arrival: RELAXED agent fetch_add on 64 group lines -> 64 leaders RELAXED
//    fetch_add root. No release/acquire orderings => compiler emits NO
//    cache-wide wbl2/inv (v2's hidden cost: ~4 cache ops x 1024 blocks/bar).
//    Ordering is provided by write-through payload stores + the vmcnt(0)
//    drain __syncthreads() already performs.
//  * exit: last leader stores phase to 8 flag lines; block polls line
//    (blockIdx.x & 7) -> ~128 pollers/line, parallel service across lines
//    (v2: 1020 pollers on ONE line = the exit-broadcast storm).
//  * counters monotonic across barriers; bailout -> visible failure, no hang.
// Layout (ints): [0]=root, [32+32x]=flag x (x<8), [320+32g]=group g (g<64).
// ---------------------------------------------------------------------------
__device__ __forceinline__ void grid_sync(int* bars, int phase) {
    __syncthreads();                                   // drains all waves' vmem
    if (threadIdx.x == 0) {
        asm volatile("s_waitcnt vmcnt(0)" ::: "memory");
        int* gc = bars + 320 + ((blockIdx.x >> 4) << 5);
        int v = __hip_atomic_fetch_add(gc, 1, __ATOMIC_RELAXED, __HIP_MEMORY_SCOPE_AGENT);
        if (v == phase * 16 - 1) {                     // last of my 16-block group
            int r = __hip_atomic_fetch_add(bars, 1, __ATOMIC_RELAXED, __HIP_MEMORY_SCOPE_AGENT);
            if (r == phase * 64 - 1)                   // last group: broadcast
                for (int xx = 0; xx < 8; xx++)
                    __hip_atomic_store(bars + 32 + 32 * xx, phase,
                                       __ATOMIC_RELAXED, __HIP_MEMORY_SCOPE_AGENT);
        }
        int* flag = bars + 32 + 32 * (blockIdx.x & 7);
        int spins = 0;
        while (__hip_atomic_load(flag, __ATOMIC_RELAXED, __HIP_MEMORY_SCOPE_AGENT) < phase) {
            if (spins < 16) __builtin_amdgcn_s_sleep(2);
            else            __builtin_amdgcn_s_sleep(32);
            if (++spins > (1 << 20)) break;            // bailout, not hang
        }
        asm volatile("" ::: "memory");                 // compiler fence only
    }
    __syncthreads();
}

// ---------------------------------------------------------------------------
// Single persistent kernel, 4 phases:
//  A: bit-pack adj rows (wt) + rank-sort (blocks 0-7) (wt)
//  B: inc bits + packed select rows (cached reads, wt writes)
//  C: blocks 0-3: greedy K-MIS (cached, L2-warm). blocks 4+: zero d_out (wt)
//     AND pool x/pos for ALL 4096 nodes (wt) — hidden under select's shadow.
//  D: slim epilogue: gather pooled rows via perm, adj^2 popcount row.
// ---------------------------------------------------------------------------
template <typename OT>
__global__ __launch_bounds__(NTHR, 4) void mega_kernel(
        const float* __restrict__ x, const float* __restrict__ adj,
        const float* __restrict__ pos, const float* __restrict__ order,
        u64* __restrict__ bitsA, u32* __restrict__ packed,
        int* __restrict__ sp2node, int* __restrict__ node2sp,
        int* __restrict__ perm, int* __restrict__ kcnt,
        float* __restrict__ xpool, float* __restrict__ pospool,
        int* __restrict__ sink, int* __restrict__ bar,
        OT* __restrict__ out, size_t out_elems)
{
    const int B = blockIdx.x, t = threadIdx.x;
    __shared__ union ShU {
        u64 keys[NN];                                   // phase A sort: 8192B
        struct {                                        // phase B: ~6.9KB
            u64 myrow[16], incw[16], part[256];
            int s2nT[16 * 65];
            u16 nbr[192];
            int cnt;
        } pb;
        struct {                                        // phase C: ~1.6KB
            u64 myrow[16];                              //   (pool blocks)
            u8 selS[NN];                                //   (select blocks)
            u16 nbr[192];
            int cnt;
        } pc;
        struct {                                        // phase D: ~6.2KB
            int p[NN];
            u64 myrow[16];
            u16 sta[NN];
        } pd;
    } sh;

    // ---------------- Phase A: pack bits (wt) + rank sort (wt) ----------------
    for (int i = 0; i < 4; i++) {
        const int id = B * 4 + i;                       // 0..4095
        const int b = id >> 10, r = id & (NN - 1);
        const size_t base = (size_t)b * NN * NN + (size_t)r * NN;
        for (int q = 0; q < 4; q++) {
            int j = q * 256 + t;
            u64 bal = __ballot(adj[base + j] != 0.0f);
            if ((t & 63) == 0) st_wt(&bitsA[((size_t)b * NN + r) * 16 + (j >> 6)], bal);
        }
    }
    if (B < 8) {                                        // 2 sort blocks per batch
        const int b = B >> 1, half = B & 1;
        for (int i = t; i < NN; i += NTHR) {
            float v = order[(size_t)b * NN + i];
            u32 ub = __float_as_uint(v);
            u32 sk = (ub & 0x80000000u) ? ~ub : (ub | 0x80000000u);
            sh.keys[i] = ((u64)sk << 32) | (u32)i;      // strict total order
        }
        __syncthreads();
        u64 mk0 = sh.keys[half * 512 + t], mk1 = sh.keys[half * 512 + 256 + t];
        int r0 = 0, r1 = 0;
        for (int m = 0; m < NN; m++) {                  // LDS broadcast reads
            u64 v = sh.keys[m];
            r0 += (v < mk0);
            r1 += (v < mk1);
        }
        int n0 = (int)(mk0 & 0xFFFFFFFFu), n1 = (int)(mk1 & 0xFFFFFFFFu);
        st_wt(&sp2node[b * NN + r0], n0); st_wt(&node2sp[b * NN + n0], r0);
        st_wt(&sp2node[b * NN + r1], n1); st_wt(&node2sp[b * NN + n1], r1);
    }
    grid_sync(bar, 1);

    // ---------------- Phase B: inc bits + packed rows ----------------
    {
        const int b = B >> 8, rbase = (B & 255) * 4;    // 4 rows, same batch
        for (int q = 0; q < 4; q++) {                   // s2nT once per block
            int j = q * 256 + t;
            sh.pb.s2nT[(j & 15) * 65 + (j >> 4)] = sp2node[b * NN + j];
        }
        for (int rr = 0; rr < 4; rr++) {
            const int r = rbase + rr;
            if (t == 0) sh.pb.cnt = 0;
            if (t < 16) sh.pb.myrow[t] = bitsA[((size_t)b * NN + r) * 16 + t];
            __syncthreads();
            for (int q = 0; q < 4; q++) {
                int j = q * 256 + t;
                if ((sh.pb.myrow[j >> 6] >> (j & 63)) & 1) {
                    int p = atomicAdd(&sh.pb.cnt, 1);
                    if (p < 192) sh.pb.nbr[p] = (u16)j;
                }
            }
            __syncthreads();
            const int c = min(sh.pb.cnt, 192);
            {   // parallel OR of neighbor rows: t = g*16 + w
                const int w = t & 15, g = t >> 4;
                u64 v = 0;
                for (int n = g; n < c; n += 16)
                    v |= bitsA[((size_t)b * NN + sh.pb.nbr[n]) * 16 + w];
                sh.pb.part[t] = v;
            }
            __syncthreads();
            if (t < 16) {
                u64 acc = sh.pb.myrow[t];
                for (int g = 0; g < 16; g++) acc |= sh.pb.part[g * 16 + t];
                sh.pb.incw[t] = acc;
            }
            __syncthreads();
            if (t < 64) {
                const int s = node2sp[b * NN + r];
                u32 e16 = 0, i16 = 0;
                for (int q = 0; q < 16; q++) {
                    int jn = sh.pb.s2nT[q * 65 + t];
                    u32 eb = (u32)((sh.pb.myrow[jn >> 6] >> (jn & 63)) & 1) | (u32)(jn == r);
                    u32 ib = (u32)((sh.pb.incw[jn >> 6] >> (jn & 63)) & 1);
                    e16 |= eb << q;
                    i16 |= ib << q;
                }
                st_wt(&packed[((size_t)b * NN + s) * 64 + t], e16 | (i16 << 16));
            }
            __syncthreads();                            // protect reuse
        }
    }
    grid_sync(bar, 2);

    // ---------- Phase C: select (blocks 0-3) || zero-out + node pooling ----------
    if (B < 4) {
        const int b = B;
        const uint4* pp = (const uint4*)(packed + (size_t)b * NN * 64);
        u32 acc = 0;                                    // warm local-XCD L2
        for (int i = t; i < NN * 16; i += NTHR) {
            uint4 v = pp[i];
            acc ^= v.x ^ v.y ^ v.z ^ v.w;
        }
        if (acc == 0xDEADBEEFu) atomicAdd(sink, 1);     // keep loads live
        __syncthreads();

        if (t < 64) {
            const int l = t;
            u32 avail = 0xFFFFu, front = (l == 0) ? 1u : 0u, sel = 0u;
            int cur = 0;                                // sorted pos 0 = argmin(order)
            for (int iter = 0; iter < 2 * NN + 8; ++iter) {
                if ((cur >> 4) == l) sel |= 1u << (cur & 15);
                u32 p = packed[((size_t)b * NN + cur) * 64 + l];
                avail &= ~(p & 0xFFFFu);                // exc (incl. diag)
                front = (front | (p >> 16)) & avail;
                u64 fb = __ballot(front != 0u);
                if (!fb) {                              // fused restart
                    front = avail;
                    fb = __ballot(front != 0u);
                    if (!fb) break;
                }
                int lf = __ffsll(fb) - 1;
                u32 f = __shfl(front, lf);
                cur = lf * 16 + (__ffs(f) - 1);
            }
            for (int q = 0; q < 16; q++) sh.pc.selS[l * 16 + q] = (sel >> q) & 1u;
        }
        __syncthreads();
        if (t < 64) {
            const int l = t;
            u32 nodesel = 0;
            const int* n2s = node2sp + b * NN;
            for (int q = 0; q < 16; q++)
                nodesel |= ((u32)sh.pc.selS[n2s[l * 16 + q]]) << q;
            int cnt_sel = __popc(nodesel);
            int ps = cnt_sel;
            for (int off = 1; off < 64; off <<= 1) {
                int v = __shfl_up(ps, off);
                if (l >= off) ps += v;
            }
            const int K = __shfl(ps, 63);
            int pos_ = ps - cnt_sel;
            u32 m = nodesel;
            while (m) { int i = __ffs(m) - 1; st_wt(&perm[b * NN + pos_], l * 16 + i); pos_++; m &= m - 1; }
            int posu = K + l * 16 - (ps - cnt_sel);
            m = (~nodesel) & 0xFFFFu;
            while (m) { int i = __ffs(m) - 1; st_wt(&perm[b * NN + posu], l * 16 + i); posu++; m &= m - 1; }
            if (l == 0) st_wt(&kcnt[b], K);
        }
    } else {
        // (a) zero d_out write-through (covers k>=K rows, tails, mask)
        const size_t nb8 = (out_elems * sizeof(OT)) >> 3;
        u64* o8 = (u64*)out;
        for (size_t i = (size_t)(B - 4) * NTHR + t; i < nb8; i += (size_t)(NBLK - 4) * NTHR)
            st_wt(o8 + i, (u64)0);
        // (b) pooled x/pos for ALL nodes — selection-independent, hidden
        //     under select's serial phase. xpool[b][n][f] = x[n] + sum_nbr x.
        for (int task = B - 4; task < BB * NN; task += NBLK - 4) {
            const int b = task & 3, n = task >> 2;
            if (t == 0) sh.pc.cnt = 0;
            if (t < 16) sh.pc.myrow[t] = bitsA[((size_t)b * NN + n) * 16 + t];
            __syncthreads();
            for (int i = 0; i < 4; i++) {
                int j = i * 256 + t;
                if ((sh.pc.myrow[j >> 6] >> (j & 63)) & 1) {
                    int pp = atomicAdd(&sh.pc.cnt, 1);
                    if (pp < 192) sh.pc.nbr[pp] = (u16)j;
                }
            }
            __syncthreads();
            const int c = min(sh.pc.cnt, 192);
            const size_t xb = (size_t)b * NN * FF;
            float acc = x[xb + (size_t)n * FF + t];
            for (int i = 0; i < c; i++) acc += x[xb + (size_t)sh.pc.nbr[i] * FF + t];
            st_wt(&xpool[((size_t)b * NN + n) * FF + t], acc);
            if (t < 3) {
                const size_t pb_ = (size_t)b * NN * 3;
                float pa = pos[pb_ + n * 3 + t];
                for (int i = 0; i < c; i++) pa += pos[pb_ + sh.pc.nbr[i] * 3 + t];
                st_wt(&pospool[((size_t)b * NN + n) * 4 + t], pa / (float)(c + 1));
            }
            __syncthreads();                            // LDS reuse
        }
    }
    grid_sync(bar, 3);

    // ---------------- Phase D: slim epilogue (k < K only) ----------------
    OT* out_x = out;
    OT* out_pos = out_x + (size_t)BB * NN * FF;
    OT* out_a = out_pos + (size_t)BB * NN * 3;
    OT* out_mask = out_a + (size_t)BB * NN * NN;

    for (int task = B; task < BB * NN; task += NBLK) {
        const int b = task & 3, k = task >> 2;          // balanced: 1 real task/block
        const int K = kcnt[b];
        if (k >= K) continue;                           // block-uniform
        const int r = perm[b * NN + k];
        OT* ox = out_x + ((size_t)b * NN + k) * FF;
        OT* op = out_pos + ((size_t)b * NN + k) * 3;
        OT* oa = out_a + ((size_t)b * NN + k) * NN;
        if (t == 0) out_mask[(size_t)b * NN + k] = fromf<OT>(1.0f);
        if (t < 16) sh.pd.myrow[t] = bitsA[((size_t)b * NN + r) * 16 + t];
        for (int q = 0; q < 4; q++) { int j = t + q * 256; sh.pd.p[j] = perm[b * NN + j]; }
        __syncthreads();

        // x_p / pos_p: gather pooled rows
        if constexpr (sizeof(OT) == 2) {
            if (t < 32) {
                const float* xr = xpool + ((size_t)b * NN + r) * FF + t * 8;
                union { u16 w[8]; uint4 v; } u;
#pragma unroll
                for (int i = 0; i < 8; i++) u.w[i] = f2bbits(xr[i]);
                ((uint4*)ox)[t] = u.v;
            }
        } else {
            ox[t] = (OT)xpool[((size_t)b * NN + r) * FF + t];
        }
        if (t < 3) op[t] = fromf<OT>(pospool[((size_t)b * NN + r) * 4 + t]);

        // coarse adj row: adj2[r,pj] = A[r,pj] + popc(row_r & row_pj)
        if constexpr (sizeof(OT) == 2) {
            for (int q = 0; q < 4; q++) {
                int jj = t + q * 256;
                float v = 0.0f;
                if (jj < K) {
                    const int pj = sh.pd.p[jj];
                    const u64* rj = bitsA + ((size_t)b * NN + pj) * 16;
                    int a2 = (int)((sh.pd.myrow[pj >> 6] >> (pj & 63)) & 1);
#pragma unroll
                    for (int w = 0; w < 16; w++)
                        a2 += __popcll(sh.pd.myrow[w] & rj[w]);
                    v = (float)a2;
                }
                sh.pd.sta[jj] = f2bbits(v);
            }
            __syncthreads();
            const int nu = (K + 7) >> 3;                // prefix only; tail pre-zeroed
            if (t < nu) ((uint4*)oa)[t] = ((const uint4*)sh.pd.sta)[t];
            __syncthreads();
        } else {
            for (int q = 0; q < 4; q++) {
                int jj = t + q * 256;
                if (jj < K) {
                    const int pj = sh.pd.p[jj];
                    const u64* rj = bitsA + ((size_t)b * NN + pj) * 16;
                    int a2 = (int)((sh.pd.myrow[pj >> 6] >> (pj & 63)) & 1);
#pragma unroll
                    for (int w = 0; w < 16; w++)
                        a2 += __popcll(sh.pd.myrow[w] & rj[w]);
                    oa[jj] = (float)a2;
                }
            }
            __syncthreads();
        }
    }
}

extern "C" void kernel_launch(void* const* d_in, const int* in_sizes, int n_in,
                              void* d_out, int out_size, void* d_ws, size_t ws_size,
                              hipStream_t stream) {
    const float* x     = (const float*)d_in[0];  // [B,N,F]
    const float* adj   = (const float*)d_in[1];  // [B,N,N]
    const float* pos   = (const float*)d_in[2];  // [B,N,3]
    const float* order = (const float*)d_in[3];  // [B,N]
    // d_in[4] = node_mask: all-true; ignored.

    char* ws = (char*)d_ws;
    size_t off = 0;
    u64* bitsA     = (u64*)(ws + off);  off += (size_t)BB * NN * 16 * 8;   // 512 KiB
    u32* packed    = (u32*)(ws + off);  off += (size_t)BB * NN * 64 * 4;   // 1 MiB
    int* sp2node   = (int*)(ws + off);  off += (size_t)BB * NN * 4;
    int* node2sp   = (int*)(ws + off);  off += (size_t)BB * NN * 4;
    int* perm      = (int*)(ws + off);  off += (size_t)BB * NN * 4;
    int* kcnt      = (int*)(ws + off);  off += 64;
    int* sink      = (int*)(ws + off);  off += 64;    // DCE-defeat, never read
    float* xpool   = (float*)(ws + off); off += (size_t)BB * NN * FF * 4;  // 4 MiB
    float* pospool = (float*)(ws + off); off += (size_t)BB * NN * 4 * 4;   // 64 KiB
    int* bar       = (int*)(ws + off);  off += 12288; // barrier: root/8 flags/64 groups

    hipMemsetAsync(bar, 0, 12288, stream);            // ws is poisoned; barrier needs 0

    bool outf32 = false;
    size_t osz = 0;
    if (hipMemPtrGetInfo(d_out, &osz) == hipSuccess)
        outf32 = (osz >= 4ull * (size_t)out_size);

    if (outf32)
        mega_kernel<float><<<NBLK, NTHR, 0, stream>>>(x, adj, pos, order, bitsA, packed,
            sp2node, node2sp, perm, kcnt, xpool, pospool, sink, bar,
            (float*)d_out, (size_t)out_size);
    else
        mega_kernel<bf16><<<NBLK, NTHR, 0, stream>>>(x, adj, pos, order, bitsA, packed,
            sp2node, node2sp, perm, kcnt, xpool, pospool, sink, bar,
            (bf16*)d_out, (size_t)out_size);
}